// Round 2
// baseline (2554.039 us; speedup 1.0000x reference)
//
#include <hip/hip_runtime.h>
#include <hip/hip_bf16.h>

// ---------------- output layout constants (floats) ----------------
constexpr size_t OFF_W1 = 1;
constexpr size_t OFF_B1 = OFF_W1 + (size_t)1024*32768;
constexpr size_t OFF_W2 = OFF_B1 + (size_t)1024*256;
constexpr size_t OFF_B2 = OFF_W2 + (size_t)1024*65536;
constexpr size_t OFF_W3 = OFF_B2 + (size_t)1024*256;
constexpr size_t OFF_B3 = OFF_W3 + (size_t)1024*32768;

// ---------------- generic GEMM: C = act(A@W + b) ----------------
// M fixed at 1024 (grid.x = 16). 64x64 tile, 4x4 per thread, K-tile 16.
__global__ __launch_bounds__(256) void gemm_kernel(
    const float* __restrict__ A, int lda,
    const float* __restrict__ W, int ldw,
    const float* __restrict__ bias,
    float* __restrict__ C, int ldc,
    int N, int K, int do_relu)
{
    __shared__ float As[16][65];
    __shared__ float Ws[16][65];
    const int tid = threadIdx.x;
    const int tx = tid & 15, ty = tid >> 4;
    const int m0 = blockIdx.x * 64, n0 = blockIdx.y * 64;
    float acc[4][4] = {};
    for (int k0 = 0; k0 < K; k0 += 16) {
        for (int l = tid; l < 1024; l += 256) {
            int mm = l >> 4, kk = l & 15;
            int gk = k0 + kk;
            As[kk][mm] = (gk < K) ? A[(size_t)(m0+mm)*lda + gk] : 0.f;
        }
        for (int l = tid; l < 1024; l += 256) {
            int kk = l >> 6, nn = l & 63;
            int gk = k0 + kk, gn = n0 + nn;
            Ws[kk][nn] = (gk < K && gn < N) ? W[(size_t)gk*ldw + gn] : 0.f;
        }
        __syncthreads();
        #pragma unroll
        for (int kk = 0; kk < 16; ++kk) {
            float a[4], b[4];
            #pragma unroll
            for (int i=0;i<4;i++) a[i] = As[kk][ty*4+i];
            #pragma unroll
            for (int j=0;j<4;j++) b[j] = Ws[kk][tx*4+j];
            #pragma unroll
            for (int i=0;i<4;i++)
                #pragma unroll
                for (int j=0;j<4;j++)
                    acc[i][j] = fmaf(a[i], b[j], acc[i][j]);
        }
        __syncthreads();
    }
    #pragma unroll
    for (int i=0;i<4;i++){
        int gm = m0 + ty*4 + i;
        #pragma unroll
        for (int j=0;j<4;j++){
            int gn = n0 + tx*4 + j;
            if (gn < N) {
                float v = acc[i][j] + (bias ? bias[gn] : 0.f);
                if (do_relu) v = fmaxf(v, 0.f);
                C[(size_t)gm*ldc + gn] = v;
            }
        }
    }
}

// ---------------- scan: h_t = l2norm(relu(h_{t-1} @ T_t)) ----------------
// 8 blocks (one per b) x 512 threads. trans (B,S,128,128) f32. structural (B,S,128) f32.
__global__ __launch_bounds__(512) void scan_kernel(
    const float* __restrict__ trans,
    const float* __restrict__ init_hidden,
    float* __restrict__ structural)
{
    __shared__ float h[128];
    __shared__ float part[512];
    __shared__ float wsum[8];
    const int b = blockIdx.x;
    const int tid = threadIdx.x;
    const int j = tid & 127, q = tid >> 7;

    if (tid < 128) part[tid] = init_hidden[tid];
    __syncthreads();
    if (tid == 0) {
        float ss = 0.f;
        for (int i = 0; i < 128; ++i) ss += part[i]*part[i];
        wsum[0] = fmaxf(sqrtf(ss), 1e-12f);
    }
    __syncthreads();
    if (tid < 128) h[tid] = part[tid] / wsum[0];
    __syncthreads();

    for (int t = 0; t < 128; ++t) {
        const float* T = trans + ((size_t)(b*128 + t) << 14);
        float accv = 0.f;
        const int i0 = q * 32;
        #pragma unroll 8
        for (int i = 0; i < 32; ++i)
            accv = fmaf(h[i0+i], T[(size_t)(i0+i)*128 + j], accv);
        part[tid] = accv;
        __syncthreads();
        float v = 0.f;
        if (tid < 128)
            v = fmaxf(part[j] + part[j+128] + part[j+256] + part[j+384], 0.f);
        float ss = v * v;
        #pragma unroll
        for (int off = 32; off > 0; off >>= 1) ss += __shfl_down(ss, off, 64);
        if ((tid & 63) == 0) wsum[tid >> 6] = ss;
        __syncthreads();
        if (tid == 0) {
            float tot = wsum[0]+wsum[1]+wsum[2]+wsum[3]+wsum[4]+wsum[5]+wsum[6]+wsum[7];
            wsum[0] = fmaxf(sqrtf(tot), 1e-12f);
        }
        __syncthreads();
        if (tid < 128) {
            float hn = v / wsum[0];
            h[tid] = hn;
            structural[(size_t)(b*128 + t)*128 + tid] = hn;
        }
        __syncthreads();
    }
}

// ---------------- mse loss: accum += scale * sum((A-B)^2), one block per row ----------------
__global__ __launch_bounds__(256) void mse_kernel(
    const float* __restrict__ A, int lda,
    const float* __restrict__ Bm, int ldb,
    int N, float scale, float* __restrict__ accum)
{
    const int m = blockIdx.x;
    float s = 0.f;
    for (int jj = threadIdx.x; jj < N; jj += 256) {
        float d = A[(size_t)m*lda + jj] - Bm[(size_t)m*ldb + jj];
        s = fmaf(d, d, s);
    }
    #pragma unroll
    for (int off = 32; off > 0; off >>= 1) s += __shfl_down(s, off, 64);
    __shared__ float w[4];
    if ((threadIdx.x & 63) == 0) w[threadIdx.x >> 6] = s;
    __syncthreads();
    if (threadIdx.x == 0) atomicAdd(accum, (w[0]+w[1]+w[2]+w[3]) * scale);
}

// ---------------- concat two 128-col f32 sources into (1024,256) ----------------
__global__ __launch_bounds__(256) void concat2_kernel(
    const float* __restrict__ s1, int ld1,
    const float* __restrict__ s2, int ld2,
    float* __restrict__ dst)
{
    const int m = blockIdx.x, jj = threadIdx.x;
    float v = (jj < 128) ? s1[(size_t)m*ld1 + jj] : s2[(size_t)m*ld2 + (jj-128)];
    dst[(size_t)m*256 + jj] = v;
}

// ---------------- build spre = [corr_s | dec_gen_s | sse] (1024 x 257) ----------------
__global__ __launch_bounds__(128) void spre_kernel(
    const float* __restrict__ out3,   // ld 256: [corr_s | corr_e]
    const float* __restrict__ out1,   // ld 256: [dec_gen_s | dec_enc]
    const float* __restrict__ encoded,// ld 128
    float* __restrict__ spre)
{
    const int m = blockIdx.x, t = threadIdx.x;
    float cs  = out3[(size_t)m*256 + t];
    float dgs = out1[(size_t)m*256 + t];
    float ce  = out3[(size_t)m*256 + 128 + t];
    float en  = encoded[(size_t)m*128 + t];
    spre[(size_t)m*257 + t]       = cs;
    spre[(size_t)m*257 + 128 + t] = dgs;
    float d = ce - en;
    float ss = d * d;
    #pragma unroll
    for (int off = 32; off > 0; off >>= 1) ss += __shfl_down(ss, off, 64);
    __shared__ float w2[2];
    if ((t & 63) == 0) w2[t >> 6] = ss;
    __syncthreads();
    if (t == 0) spre[(size_t)m*257 + 256] = w2[0] + w2[1];
}

// ---------------- inf_s + consistency loss ----------------
__global__ __launch_bounds__(128) void infs_kernel(
    const float* __restrict__ out1,   // dec_gen_s at ld 256
    const float* __restrict__ out3,   // corr_s at ld 256
    const float* __restrict__ pvar,   // ld 128
    const float* __restrict__ ratio_p,
    float* __restrict__ inf_s,        // ld 128
    float scale, float* __restrict__ accum)
{
    const int m = blockIdx.x, t = threadIdx.x;
    float ratio = ratio_p[0];
    float dgs = out1[(size_t)m*256 + t];
    float cs  = out3[(size_t)m*256 + t];
    float pv  = pvar[(size_t)m*128 + t];
    float delta = (cs - dgs) * ratio * pv;
    inf_s[(size_t)m*128 + t] = dgs + delta;
    float ss = delta * delta;
    #pragma unroll
    for (int off = 32; off > 0; off >>= 1) ss += __shfl_down(ss, off, 64);
    __shared__ float w2[2];
    if ((t & 63) == 0) w2[t >> 6] = ss;
    __syncthreads();
    if (t == 0) atomicAdd(accum, (w2[0] + w2[1]) * scale);
}

// ---------------- per-sample meta-gradients ----------------
// 1024 blocks (one per (b,s)) x 256 threads.
__global__ __launch_bounds__(256) void grad_kernel(
    const float* __restrict__ keys, const float* __restrict__ values,
    const float* __restrict__ mW1, const float* __restrict__ mb1,
    const float* __restrict__ mW2, const float* __restrict__ mb2,
    const float* __restrict__ mW3, const float* __restrict__ mb3,
    float* __restrict__ out)
{
    __shared__ float ks[128], vs[128], h1[256], h2[256], dob[128], dh2[256], dh1[256];
    const int bs = blockIdx.x, t = threadIdx.x;
    if (t < 128) { ks[t] = keys[(size_t)bs*128 + t]; vs[t] = values[(size_t)bs*128 + t]; }
    __syncthreads();
    // forward
    float a = mb1[t];
    #pragma unroll 4
    for (int i = 0; i < 128; ++i) a = fmaf(ks[i], mW1[i*256 + t], a);
    h1[t] = fmaxf(a, 0.f);
    __syncthreads();
    a = mb2[t];
    #pragma unroll 4
    for (int i = 0; i < 256; ++i) a = fmaf(h1[i], mW2[i*256 + t], a);
    h2[t] = fmaxf(a, 0.f);
    __syncthreads();
    if (t < 128) {
        a = mb3[t];
        #pragma unroll 4
        for (int i = 0; i < 256; ++i) a = fmaf(h2[i], mW3[i*128 + t], a);
        dob[t] = 2.f * (a - vs[t]) * (1.f/128.f);
    }
    __syncthreads();
    // backward
    a = 0.f;
    #pragma unroll 4
    for (int jj = 0; jj < 128; ++jj) a = fmaf(mW3[t*128 + jj], dob[jj], a);
    dh2[t] = (h2[t] > 0.f) ? a : 0.f;
    __syncthreads();
    a = 0.f;
    #pragma unroll 4
    for (int jj = 0; jj < 256; ++jj) a = fmaf(mW2[t*256 + jj], dh2[jj], a);
    dh1[t] = (h1[t] > 0.f) ? a : 0.f;
    __syncthreads();
    // writes (all coalesced over consecutive e)
    {
        float* p = out + OFF_W1 + (size_t)bs*32768;
        for (int e = t; e < 32768; e += 256) {
            int i = e >> 8, jj = e & 255;
            p[e] = ks[i] * dh1[jj];
        }
    }
    out[OFF_B1 + (size_t)bs*256 + t] = dh1[t];
    {
        float* p = out + OFF_W2 + (size_t)bs*65536;
        for (int e = t; e < 65536; e += 256) {
            int i = e >> 8, jj = e & 255;
            p[e] = h1[i] * dh2[jj];
        }
    }
    out[OFF_B2 + (size_t)bs*256 + t] = dh2[t];
    {
        float* p = out + OFF_W3 + (size_t)bs*32768;
        for (int e = t; e < 32768; e += 256) {
            int i = e >> 7, jj = e & 127;
            p[e] = h2[i] * dob[jj];
        }
    }
    if (t < 128) out[OFF_B3 + (size_t)bs*128 + t] = dob[t];
}

__global__ void zero_kernel(float* acc) {
    if (threadIdx.x < 8) acc[threadIdx.x] = 0.f;
}

__global__ void total_kernel(const float* acc, float* out) {
    if (threadIdx.x == 0)
        out[0] = acc[0] + acc[1] + acc[2] + acc[3];
}

// ---------------- host ----------------
static inline void gemmF(const float* A, int lda, const float* W, int ldw, const float* bias,
                         float* C, int N, int K, int relu, hipStream_t s)
{
    dim3 g(16, (N + 63) / 64);
    gemm_kernel<<<g, 256, 0, s>>>(A, lda, W, ldw, bias, C, N, N, K, relu);
}

extern "C" void kernel_launch(void* const* d_in, const int* in_sizes, int n_in,
                              void* d_out, int out_size, void* d_ws, size_t ws_size,
                              hipStream_t stream)
{
    const float* sensory     = (const float*)d_in[0];
    const float* actions     = (const float*)d_in[1];
    const float* init_hidden = (const float*)d_in[2];
    const float* tW1 = (const float*)d_in[3];  const float* tb1 = (const float*)d_in[4];
    const float* tW2 = (const float*)d_in[5];  const float* tb2 = (const float*)d_in[6];
    const float* tW3 = (const float*)d_in[7];  const float* tb3 = (const float*)d_in[8];
    const float* enc_w = (const float*)d_in[9];  const float* enc_b = (const float*)d_in[10];
    const float* dec_w = (const float*)d_in[11]; const float* dec_b = (const float*)d_in[12];
    const float* q_w = (const float*)d_in[13];
    const float* k_w = (const float*)d_in[14];
    const float* v_w = (const float*)d_in[15];
    const float* mW1 = (const float*)d_in[16]; const float* mb1 = (const float*)d_in[17];
    const float* mW2 = (const float*)d_in[18]; const float* mb2 = (const float*)d_in[19];
    const float* mW3 = (const float*)d_in[20]; const float* mb3 = (const float*)d_in[21];
    const float* oW1 = (const float*)d_in[22]; const float* ob1 = (const float*)d_in[23];
    const float* oW2 = (const float*)d_in[24]; const float* ob2 = (const float*)d_in[25];
    const float* oW3 = (const float*)d_in[26]; const float* ob3 = (const float*)d_in[27];
    const float* sW1 = (const float*)d_in[28]; const float* sb1 = (const float*)d_in[29];
    const float* sW2 = (const float*)d_in[30]; const float* sb2 = (const float*)d_in[31];
    const float* sW3 = (const float*)d_in[32]; const float* sb3 = (const float*)d_in[33];
    const float* ratio = (const float*)d_in[34];
    float* out = (float*)d_out;

    // workspace layout (floats)
    float* Wsp = (float*)d_ws;
    size_t off = 0;
    float* acc  = Wsp + off; off += 16;
    float* a1   = Wsp + off; off += (size_t)1024*128;
    float* a2   = Wsp + off; off += (size_t)1024*128;
    float* trans= Wsp + off; off += (size_t)1024*16384;
    float* structural = Wsp + off; off += (size_t)1024*128;
    float* encoded    = Wsp + off; off += (size_t)1024*128;
    float* qbuf = Wsp + off; off += (size_t)1024*128;
    float* m1b  = Wsp + off; off += (size_t)1024*256;
    float* m2b  = Wsp + off; off += (size_t)1024*256;
    float* rb   = Wsp + off; off += (size_t)1024*128;
    float* o1b  = Wsp + off; off += (size_t)1024*256;
    float* o2b  = Wsp + off; off += (size_t)1024*256;
    float* out1 = Wsp + off; off += (size_t)1024*256;
    float* out2 = Wsp + off; off += (size_t)1024*256;
    float* out3 = Wsp + off; off += (size_t)1024*256;
    float* out4 = Wsp + off; off += (size_t)1024*256;
    float* joint= Wsp + off; off += (size_t)1024*256;
    float* spre = Wsp + off; off += (size_t)1024*257;
    float* sv1  = Wsp + off; off += (size_t)1024*256;
    float* sv2  = Wsp + off; off += (size_t)1024*256;
    float* pvar = Wsp + off; off += (size_t)1024*128;
    float* infs = Wsp + off; off += (size_t)1024*128;
    float* deco = Wsp + off; off += (size_t)1024*512;
    float* keys = Wsp + off; off += (size_t)1024*128;
    float* vals = Wsp + off; off += (size_t)1024*128;

    zero_kernel<<<1, 64, 0, stream>>>(acc);

    // PathIntegration transitions MLP
    gemmF(actions, 32, tW1, 128, tb1, a1, 128, 32, 1, stream);
    gemmF(a1, 128, tW2, 128, tb2, a2, 128, 128, 1, stream);
    gemmF(a2, 128, tW3, 16384, tb3, trans, 16384, 128, 0, stream);
    // encoder (linear, no relu)
    gemmF(sensory, 512, enc_w, 128, enc_b, encoded, 128, 512, 0, stream);
    // scan
    scan_kernel<<<8, 512, 0, stream>>>(trans, init_hidden, structural);

    // retrieve helper (sequence of GEMMs through shared scratch)
    auto retrieve = [&](const float* qA, int qlda, const float* qW, int Kq, float* outB) {
        gemmF(qA, qlda, qW, 128, nullptr, qbuf, 128, Kq, 0, stream);
        gemmF(qbuf, 128, mW1, 256, mb1, m1b, 256, 128, 1, stream);
        gemmF(m1b, 256, mW2, 256, mb2, m2b, 256, 256, 1, stream);
        gemmF(m2b, 256, mW3, 128, mb3, rb, 128, 256, 0, stream);
        gemmF(rb, 128, oW1, 256, ob1, o1b, 256, 128, 1, stream);
        gemmF(o1b, 256, oW2, 256, ob2, o2b, 256, 256, 1, stream);
        gemmF(o2b, 256, oW3, 256, ob3, outB, 256, 256, 0, stream);
    };

    // generative branch: retrieve(structural, 0)
    retrieve(structural, 128, q_w, 128, out1);
    gemmF(out1 + 128, 256, dec_w, 512, dec_b, deco, 512, 128, 0, stream);
    mse_kernel<<<1024, 256, 0, stream>>>(deco, 512, sensory, 512, 512,
                                         1.f/524288.f, acc + 0);

    // relational branch: retrieve(0, encoded), used twice -> scale 2x
    retrieve(encoded, 128, q_w + 128*128, 128, out2);
    mse_kernel<<<1024, 256, 0, stream>>>(out2, 256, structural, 128, 128,
                                         2.f/131072.f, acc + 1);

    // consistency: retrieve(dec_gen_s, encoded)
    concat2_kernel<<<1024, 256, 0, stream>>>(out1, 256, encoded, 128, joint);
    retrieve(joint, 256, q_w, 256, out3);
    spre_kernel<<<1024, 128, 0, stream>>>(out3, out1, encoded, spre);
    gemmF(spre, 257, sW1, 256, sb1, sv1, 256, 257, 1, stream);
    gemmF(sv1, 256, sW2, 256, sb2, sv2, 256, 256, 1, stream);
    gemmF(sv2, 256, sW3, 128, sb3, pvar, 128, 256, 0, stream);
    infs_kernel<<<1024, 128, 0, stream>>>(out1, out3, pvar, ratio, infs,
                                          1.f/131072.f, acc + 2);

    // inference branch: retrieve(inf_s, 0)
    retrieve(infs, 128, q_w, 128, out4);
    gemmF(out4 + 128, 256, dec_w, 512, dec_b, deco, 512, 128, 0, stream);
    mse_kernel<<<1024, 256, 0, stream>>>(deco, 512, sensory, 512, 512,
                                         1.f/524288.f, acc + 3);

    // fast-weight memory grads
    concat2_kernel<<<1024, 256, 0, stream>>>(out4, 256, encoded, 128, joint);
    gemmF(joint, 256, k_w, 128, nullptr, keys, 128, 256, 0, stream);
    gemmF(joint, 256, v_w, 128, nullptr, vals, 128, 256, 0, stream);
    grad_kernel<<<1024, 256, 0, stream>>>(keys, vals, mW1, mb1, mW2, mb2, mW3, mb3, out);

    total_kernel<<<1, 64, 0, stream>>>(acc, out);
}

// Round 3
// 1536.931 us; speedup vs baseline: 1.6618x; 1.6618x over previous
//
#include <hip/hip_runtime.h>
#include <hip/hip_bf16.h>

// ---------------- output layout constants (floats) ----------------
constexpr size_t OFF_W1 = 1;
constexpr size_t OFF_B1 = OFF_W1 + (size_t)1024*32768;
constexpr size_t OFF_W2 = OFF_B1 + (size_t)1024*256;
constexpr size_t OFF_B2 = OFF_W2 + (size_t)1024*65536;
constexpr size_t OFF_W3 = OFF_B2 + (size_t)1024*256;
constexpr size_t OFF_B3 = OFF_W3 + (size_t)1024*32768;

// ================= generic f32 GEMM (used for trans MLP / encoder / decoder) =================
__global__ __launch_bounds__(256) void gemm_kernel(
    const float* __restrict__ A, int lda,
    const float* __restrict__ W, int ldw,
    const float* __restrict__ bias,
    float* __restrict__ C, int ldc,
    int N, int K, int do_relu)
{
    __shared__ float As[16][65];
    __shared__ float Ws[16][65];
    const int tid = threadIdx.x;
    const int tx = tid & 15, ty = tid >> 4;
    const int m0 = blockIdx.x * 64, n0 = blockIdx.y * 64;
    float acc[4][4] = {};
    for (int k0 = 0; k0 < K; k0 += 16) {
        for (int l = tid; l < 1024; l += 256) {
            int mm = l >> 4, kk = l & 15;
            int gk = k0 + kk;
            As[kk][mm] = (gk < K) ? A[(size_t)(m0+mm)*lda + gk] : 0.f;
        }
        for (int l = tid; l < 1024; l += 256) {
            int kk = l >> 6, nn = l & 63;
            int gk = k0 + kk, gn = n0 + nn;
            Ws[kk][nn] = (gk < K && gn < N) ? W[(size_t)gk*ldw + gn] : 0.f;
        }
        __syncthreads();
        #pragma unroll
        for (int kk = 0; kk < 16; ++kk) {
            float a[4], b[4];
            #pragma unroll
            for (int i=0;i<4;i++) a[i] = As[kk][ty*4+i];
            #pragma unroll
            for (int j=0;j<4;j++) b[j] = Ws[kk][tx*4+j];
            #pragma unroll
            for (int i=0;i<4;i++)
                #pragma unroll
                for (int j=0;j<4;j++)
                    acc[i][j] = fmaf(a[i], b[j], acc[i][j]);
        }
        __syncthreads();
    }
    #pragma unroll
    for (int i=0;i<4;i++){
        int gm = m0 + ty*4 + i;
        #pragma unroll
        for (int j=0;j<4;j++){
            int gn = n0 + tx*4 + j;
            if (gn < N) {
                float v = acc[i][j] + (bias ? bias[gn] : 0.f);
                if (do_relu) v = fmaxf(v, 0.f);
                C[(size_t)gm*ldc + gn] = v;
            }
        }
    }
}

// ================= scan v2: register double-buffered T =================
// 8 blocks x 512 threads. thread: q=tid>>5 owns i-range [q*8,q*8+8), g=tid&31 owns cols jj=g*4..+3
__global__ __launch_bounds__(512) void scan_kernel2(
    const float* __restrict__ trans,
    const float* __restrict__ init_hidden,
    float* __restrict__ structural)
{
    __shared__ float h[128];
    __shared__ float psum[16*128];
    const int b = blockIdx.x, tid = threadIdx.x;
    const int q = tid >> 5, g = tid & 31;
    const int jj = g * 4, i0 = q * 8;

    if (tid < 32) {
        float4 v = *(const float4*)&init_hidden[tid*4];
        float ss = v.x*v.x + v.y*v.y + v.z*v.z + v.w*v.w;
        ss += __shfl_xor(ss, 16); ss += __shfl_xor(ss, 8); ss += __shfl_xor(ss, 4);
        ss += __shfl_xor(ss, 2);  ss += __shfl_xor(ss, 1);
        float inv = 1.f / fmaxf(sqrtf(ss), 1e-12f);
        v.x *= inv; v.y *= inv; v.z *= inv; v.w *= inv;
        *(float4*)&h[tid*4] = v;
    }
    __syncthreads();

    float4 cur[8], nxt[8];
    {
        const float* T0 = trans + ((size_t)(b*128) << 14);
        #pragma unroll
        for (int i = 0; i < 8; ++i)
            cur[i] = *(const float4*)&T0[(size_t)(i0+i)*128 + jj];
    }

    for (int t = 0; t < 128; ++t) {
        const int tn = (t < 127) ? t + 1 : 127;
        const float* Tn = trans + ((size_t)(b*128 + tn) << 14);
        #pragma unroll
        for (int i = 0; i < 8; ++i)
            nxt[i] = *(const float4*)&Tn[(size_t)(i0+i)*128 + jj];

        float4 acc = make_float4(0.f,0.f,0.f,0.f);
        #pragma unroll
        for (int i = 0; i < 8; ++i) {
            float hv = h[i0+i];
            acc.x = fmaf(hv, cur[i].x, acc.x);
            acc.y = fmaf(hv, cur[i].y, acc.y);
            acc.z = fmaf(hv, cur[i].z, acc.z);
            acc.w = fmaf(hv, cur[i].w, acc.w);
        }
        *(float4*)&psum[q*128 + jj] = acc;
        __syncthreads();
        if (tid < 32) {
            float4 s = make_float4(0.f,0.f,0.f,0.f);
            #pragma unroll
            for (int qq = 0; qq < 16; ++qq) {
                float4 p = *(const float4*)&psum[qq*128 + tid*4];
                s.x += p.x; s.y += p.y; s.z += p.z; s.w += p.w;
            }
            s.x = fmaxf(s.x, 0.f); s.y = fmaxf(s.y, 0.f);
            s.z = fmaxf(s.z, 0.f); s.w = fmaxf(s.w, 0.f);
            float ss = s.x*s.x + s.y*s.y + s.z*s.z + s.w*s.w;
            ss += __shfl_xor(ss, 16); ss += __shfl_xor(ss, 8); ss += __shfl_xor(ss, 4);
            ss += __shfl_xor(ss, 2);  ss += __shfl_xor(ss, 1);
            float inv = 1.f / fmaxf(sqrtf(ss), 1e-12f);
            s.x *= inv; s.y *= inv; s.z *= inv; s.w *= inv;
            *(float4*)&h[tid*4] = s;
            *(float4*)&structural[((size_t)(b*128 + t))*128 + tid*4] = s;
        }
        __syncthreads();
        #pragma unroll
        for (int i = 0; i < 8; ++i) cur[i] = nxt[i];
    }
}

// ================= fused-MLP building blocks (LDS activations, streamed weights) =================
// stage 128-wide rows into LDS buf[rows][128]; src may be null (zeros)
__device__ __forceinline__ void stage_rows(float* buf, const float* src, int ld,
                                           int row0, int rows, int t)
{
    int r = t >> 5; if (rows == 4) r &= 3;
    const int k4 = (t & 31) * 4;
    float4 v = make_float4(0.f,0.f,0.f,0.f);
    if (src) v = *(const float4*)&src[(size_t)(row0 + r)*ld + k4];
    *(float4*)&buf[r*128 + k4] = v;
}

// N=256, 8 rows (2 rows/thread)
__device__ __forceinline__ void layer_n256_r8(
    const float* __restrict__ W, const float* __restrict__ bias, int K,
    const float* __restrict__ x, int xs, float* __restrict__ y, int relu, int t)
{
    const int c4 = (t & 63) * 4;
    const int r0 = (t >> 6) * 2;
    float4 a0 = bias ? *(const float4*)&bias[c4] : make_float4(0.f,0.f,0.f,0.f);
    float4 a1 = a0;
    const float* x0 = x + r0 * xs;
    const float* x1 = x0 + xs;
    for (int k = 0; k < K; ++k) {
        float4 w = *(const float4*)&W[(size_t)k*256 + c4];
        float xa = x0[k], xb = x1[k];
        a0.x = fmaf(w.x, xa, a0.x); a0.y = fmaf(w.y, xa, a0.y);
        a0.z = fmaf(w.z, xa, a0.z); a0.w = fmaf(w.w, xa, a0.w);
        a1.x = fmaf(w.x, xb, a1.x); a1.y = fmaf(w.y, xb, a1.y);
        a1.z = fmaf(w.z, xb, a1.z); a1.w = fmaf(w.w, xb, a1.w);
    }
    if (relu) {
        a0.x=fmaxf(a0.x,0.f); a0.y=fmaxf(a0.y,0.f); a0.z=fmaxf(a0.z,0.f); a0.w=fmaxf(a0.w,0.f);
        a1.x=fmaxf(a1.x,0.f); a1.y=fmaxf(a1.y,0.f); a1.z=fmaxf(a1.z,0.f); a1.w=fmaxf(a1.w,0.f);
    }
    *(float4*)&y[r0*256 + c4] = a0;
    *(float4*)&y[(r0+1)*256 + c4] = a1;
}

// N=256, 4 rows (1 row/thread), optional relu-mask (d = d * (mask>0))
__device__ __forceinline__ void layer_n256_r4(
    const float* __restrict__ W, const float* __restrict__ bias, int K,
    const float* __restrict__ x, int xs, float* __restrict__ y, int relu,
    const float* __restrict__ mask, int t)
{
    const int c4 = (t & 63) * 4;
    const int r = t >> 6;
    float4 a = bias ? *(const float4*)&bias[c4] : make_float4(0.f,0.f,0.f,0.f);
    const float* xr = x + r * xs;
    for (int k = 0; k < K; ++k) {
        float4 w = *(const float4*)&W[(size_t)k*256 + c4];
        float xa = xr[k];
        a.x = fmaf(w.x, xa, a.x); a.y = fmaf(w.y, xa, a.y);
        a.z = fmaf(w.z, xa, a.z); a.w = fmaf(w.w, xa, a.w);
    }
    if (relu) {
        a.x=fmaxf(a.x,0.f); a.y=fmaxf(a.y,0.f); a.z=fmaxf(a.z,0.f); a.w=fmaxf(a.w,0.f);
    }
    if (mask) {
        float4 m = *(const float4*)&mask[r*256 + c4];
        a.x = (m.x > 0.f) ? a.x : 0.f; a.y = (m.y > 0.f) ? a.y : 0.f;
        a.z = (m.z > 0.f) ? a.z : 0.f; a.w = (m.w > 0.f) ? a.w : 0.f;
    }
    *(float4*)&y[r*256 + c4] = a;
}

// N=128 layer (1 row/thread; rows=4 duplicates upper half harmlessly)
__device__ __forceinline__ void layer_n128(
    const float* __restrict__ W, const float* __restrict__ bias, int K,
    const float* __restrict__ x, int xs, float* __restrict__ y, int ys, int relu,
    int rows, int t)
{
    const int c4 = (t & 31) * 4;
    int r = t >> 5; if (rows == 4) r &= 3;
    float4 a = bias ? *(const float4*)&bias[c4] : make_float4(0.f,0.f,0.f,0.f);
    const float* xr = x + r * xs;
    for (int k = 0; k < K; ++k) {
        float4 w = *(const float4*)&W[(size_t)k*128 + c4];
        float xa = xr[k];
        a.x = fmaf(w.x, xa, a.x); a.y = fmaf(w.y, xa, a.y);
        a.z = fmaf(w.z, xa, a.z); a.w = fmaf(w.w, xa, a.w);
    }
    if (relu) {
        a.x=fmaxf(a.x,0.f); a.y=fmaxf(a.y,0.f); a.z=fmaxf(a.z,0.f); a.w=fmaxf(a.w,0.f);
    }
    *(float4*)&y[r*ys + c4] = a;
}

// dual-source projection: y = [xA|xB] @ W, W is (256)x128 row-major, no bias/relu
__device__ __forceinline__ void layer_n128_dual(
    const float* __restrict__ W,
    const float* __restrict__ xA, const float* __restrict__ xB,
    float* __restrict__ y, int rows, int t)
{
    const int c4 = (t & 31) * 4;
    int r = t >> 5; if (rows == 4) r &= 3;
    float4 a = make_float4(0.f,0.f,0.f,0.f);
    const float* xa_ = xA + r * 128;
    const float* xb_ = xB + r * 128;
    for (int k = 0; k < 128; ++k) {
        float4 w = *(const float4*)&W[(size_t)k*128 + c4];
        float v = xa_[k];
        a.x = fmaf(w.x, v, a.x); a.y = fmaf(w.y, v, a.y);
        a.z = fmaf(w.z, v, a.z); a.w = fmaf(w.w, v, a.w);
    }
    for (int k = 0; k < 128; ++k) {
        float4 w = *(const float4*)&W[(size_t)(128+k)*128 + c4];
        float v = xb_[k];
        a.x = fmaf(w.x, v, a.x); a.y = fmaf(w.y, v, a.y);
        a.z = fmaf(w.z, v, a.z); a.w = fmaf(w.w, v, a.w);
    }
    *(float4*)&y[r*128 + c4] = a;
}

// ================= fused retrieve: q-proj + 6 MLP layers, out (1024x256) =================
__global__ __launch_bounds__(256) void fused_retrieve_kernel(
    const float* __restrict__ A1, int ld1,
    const float* __restrict__ A2, int ld2,
    const float* __restrict__ qw,
    const float* __restrict__ mW1, const float* __restrict__ mb1,
    const float* __restrict__ mW2, const float* __restrict__ mb2,
    const float* __restrict__ mW3, const float* __restrict__ mb3,
    const float* __restrict__ oW1, const float* __restrict__ ob1,
    const float* __restrict__ oW2, const float* __restrict__ ob2,
    const float* __restrict__ oW3, const float* __restrict__ ob3,
    float* __restrict__ outB)
{
    __shared__ float bufA[8*128], bufB[8*128], ping[8*256], pong[8*256];
    const int t = threadIdx.x;
    const int row0 = blockIdx.x * 8;

    stage_rows(bufA, A1, ld1, row0, 8, t);
    stage_rows(bufB, A2, ld2, row0, 8, t);
    __syncthreads();
    layer_n128_dual(qw, bufA, bufB, ping, 8, t);                 // q -> ping(128)
    __syncthreads();
    layer_n256_r8(mW1, mb1, 128, ping, 128, pong, 1, t);         // h1 -> pong(256)
    __syncthreads();
    layer_n256_r8(mW2, mb2, 256, pong, 256, ping, 1, t);         // h2 -> ping(256)
    __syncthreads();
    layer_n128(mW3, mb3, 256, ping, 256, pong, 128, 0, 8, t);    // r -> pong(128)
    __syncthreads();
    layer_n256_r8(oW1, ob1, 128, pong, 128, ping, 1, t);         // o1 -> ping(256)
    __syncthreads();
    layer_n256_r8(oW2, ob2, 256, ping, 256, pong, 1, t);         // o2 -> pong(256)
    __syncthreads();
    layer_n256_r8(oW3, ob3, 256, pong, 256, ping, 0, t);         // out -> ping(256)
    __syncthreads();
    #pragma unroll
    for (int e = t; e < 512; e += 256) {
        int r = e >> 6, c = (e & 63) * 4;
        *(float4*)&outB[(size_t)(row0+r)*256 + c] = *(const float4*)&ping[r*256 + c];
    }
}

// ================= fused svar: spre build + 3 layers -> pvar (1024x128) =================
__global__ __launch_bounds__(256) void fused_svar_kernel(
    const float* __restrict__ out3,    // [corr_s | corr_e] ld 256
    const float* __restrict__ out1,    // [dec_gen_s | .] ld 256
    const float* __restrict__ encoded, // ld 128
    const float* __restrict__ sW1, const float* __restrict__ sb1,
    const float* __restrict__ sW2, const float* __restrict__ sb2,
    const float* __restrict__ sW3, const float* __restrict__ sb3,
    float* __restrict__ pvar)
{
    __shared__ float bufA[8*128], bufB[8*128], sse[8], ping[8*256], pong[8*256];
    const int t = threadIdx.x;
    const int row0 = blockIdx.x * 8;
    const int r = t >> 5, k4 = (t & 31) * 4;

    // stage corr_s, dec_gen_s; compute sse per row
    {
        float4 cs = *(const float4*)&out3[(size_t)(row0+r)*256 + k4];
        float4 ds = *(const float4*)&out1[(size_t)(row0+r)*256 + k4];
        *(float4*)&bufA[r*128 + k4] = cs;
        *(float4*)&bufB[r*128 + k4] = ds;
        float4 ce = *(const float4*)&out3[(size_t)(row0+r)*256 + 128 + k4];
        float4 en = *(const float4*)&encoded[(size_t)(row0+r)*128 + k4];
        float dx = ce.x-en.x, dy = ce.y-en.y, dz = ce.z-en.z, dw = ce.w-en.w;
        float ss = dx*dx + dy*dy + dz*dz + dw*dw;
        ss += __shfl_xor(ss, 16); ss += __shfl_xor(ss, 8); ss += __shfl_xor(ss, 4);
        ss += __shfl_xor(ss, 2);  ss += __shfl_xor(ss, 1);
        if ((t & 31) == 0) sse[r] = ss;
    }
    __syncthreads();
    // L1: K=257 [bufA | bufB | sse] @ sW1 -> ping(256), relu
    {
        const int c4 = (t & 63) * 4;
        const int r0 = (t >> 6) * 2;
        float4 a0 = *(const float4*)&sb1[c4];
        float4 a1 = a0;
        for (int k = 0; k < 128; ++k) {
            float4 w = *(const float4*)&sW1[(size_t)k*256 + c4];
            float xa = bufA[r0*128 + k], xb = bufA[(r0+1)*128 + k];
            a0.x=fmaf(w.x,xa,a0.x); a0.y=fmaf(w.y,xa,a0.y); a0.z=fmaf(w.z,xa,a0.z); a0.w=fmaf(w.w,xa,a0.w);
            a1.x=fmaf(w.x,xb,a1.x); a1.y=fmaf(w.y,xb,a1.y); a1.z=fmaf(w.z,xb,a1.z); a1.w=fmaf(w.w,xb,a1.w);
        }
        for (int k = 0; k < 128; ++k) {
            float4 w = *(const float4*)&sW1[(size_t)(128+k)*256 + c4];
            float xa = bufB[r0*128 + k], xb = bufB[(r0+1)*128 + k];
            a0.x=fmaf(w.x,xa,a0.x); a0.y=fmaf(w.y,xa,a0.y); a0.z=fmaf(w.z,xa,a0.z); a0.w=fmaf(w.w,xa,a0.w);
            a1.x=fmaf(w.x,xb,a1.x); a1.y=fmaf(w.y,xb,a1.y); a1.z=fmaf(w.z,xb,a1.z); a1.w=fmaf(w.w,xb,a1.w);
        }
        {
            float4 w = *(const float4*)&sW1[(size_t)256*256 + c4];
            float xa = sse[r0], xb = sse[r0+1];
            a0.x=fmaf(w.x,xa,a0.x); a0.y=fmaf(w.y,xa,a0.y); a0.z=fmaf(w.z,xa,a0.z); a0.w=fmaf(w.w,xa,a0.w);
            a1.x=fmaf(w.x,xb,a1.x); a1.y=fmaf(w.y,xb,a1.y); a1.z=fmaf(w.z,xb,a1.z); a1.w=fmaf(w.w,xb,a1.w);
        }
        a0.x=fmaxf(a0.x,0.f); a0.y=fmaxf(a0.y,0.f); a0.z=fmaxf(a0.z,0.f); a0.w=fmaxf(a0.w,0.f);
        a1.x=fmaxf(a1.x,0.f); a1.y=fmaxf(a1.y,0.f); a1.z=fmaxf(a1.z,0.f); a1.w=fmaxf(a1.w,0.f);
        *(float4*)&ping[r0*256 + c4] = a0;
        *(float4*)&ping[(r0+1)*256 + c4] = a1;
    }
    __syncthreads();
    layer_n256_r8(sW2, sb2, 256, ping, 256, pong, 1, t);
    __syncthreads();
    layer_n128(sW3, sb3, 256, pong, 256, ping, 128, 0, 8, t);
    __syncthreads();
    {
        int rr = t >> 5, c = (t & 31) * 4;
        *(float4*)&pvar[(size_t)(row0+rr)*128 + c] = *(const float4*)&ping[rr*128 + c];
    }
}

// ================= fused grad: keys/vals proj + meta fwd/bwd + grad writes =================
__global__ __launch_bounds__(256) void fused_grad_kernel(
    const float* __restrict__ A1,       // out4 (final_s in cols 0..127), ld 256
    const float* __restrict__ encoded,  // ld 128
    const float* __restrict__ k_w, const float* __restrict__ v_w,
    const float* __restrict__ mW1, const float* __restrict__ mb1,
    const float* __restrict__ mW2, const float* __restrict__ mb2,
    const float* __restrict__ mW3, const float* __restrict__ mb3,
    const float* __restrict__ T2,       // mW2 transposed (256x256)
    const float* __restrict__ T3,       // mW3 transposed (128x256)
    float* __restrict__ out)
{
    __shared__ float bufA[4*128], bufB[4*128], ks[4*128], vs[4*128];
    __shared__ float h1[4*256], h2[4*256], dob[4*128], dh2[4*256], dh1[4*256];
    const int t = threadIdx.x;
    const int row0 = blockIdx.x * 4;

    stage_rows(bufA, A1, 256, row0, 4, t);
    stage_rows(bufB, encoded, 128, row0, 4, t);
    __syncthreads();
    layer_n128_dual(k_w, bufA, bufB, ks, 4, t);
    layer_n128_dual(v_w, bufA, bufB, vs, 4, t);
    __syncthreads();
    layer_n256_r4(mW1, mb1, 128, ks, 128, h1, 1, nullptr, t);
    __syncthreads();
    layer_n256_r4(mW2, mb2, 256, h1, 256, h2, 1, nullptr, t);
    __syncthreads();
    layer_n128(mW3, mb3, 256, h2, 256, dob, 128, 0, 4, t);   // pre -> dob buffer
    __syncthreads();
    for (int e = t; e < 512; e += 256)
        dob[e] = (dob[e] - vs[e]) * 0.015625f;               // 2/128
    __syncthreads();
    layer_n256_r4(T3, nullptr, 128, dob, 128, dh2, 0, h2, t);
    __syncthreads();
    layer_n256_r4(T2, nullptr, 256, dh2, 256, dh1, 0, h1, t);
    __syncthreads();

    #pragma unroll
    for (int r = 0; r < 4; ++r) {
        const size_t row = row0 + r;
        {
            const float dv = dh1[r*256 + t];
            float* p = out + OFF_W1 + row*32768;
            for (int i = 0; i < 128; ++i)
                p[(size_t)i*256 + t] = ks[r*128 + i] * dv;
            out[OFF_B1 + row*256 + t] = dv;
        }
        {
            const float d2 = dh2[r*256 + t];
            float* p = out + OFF_W2 + row*65536;
            for (int i = 0; i < 256; ++i)
                p[(size_t)i*256 + t] = h1[r*256 + i] * d2;
            out[OFF_B2 + row*256 + t] = d2;
        }
        {
            const int j = t & 127, ih = t >> 7;
            const float d3 = dob[r*128 + j];
            float* p = out + OFF_W3 + row*32768;
            for (int i = ih*128; i < ih*128 + 128; ++i)
                p[(size_t)i*128 + j] = h2[r*256 + i] * d3;
            if (t < 128) out[OFF_B3 + row*128 + t] = dob[r*128 + t];
        }
    }
}

// ================= misc small kernels =================
__global__ __launch_bounds__(256) void mse_kernel(
    const float* __restrict__ A, int lda,
    const float* __restrict__ Bm, int ldb,
    int N, float scale, float* __restrict__ accum)
{
    const int m = blockIdx.x;
    float s = 0.f;
    for (int jj = threadIdx.x; jj < N; jj += 256) {
        float d = A[(size_t)m*lda + jj] - Bm[(size_t)m*ldb + jj];
        s = fmaf(d, d, s);
    }
    #pragma unroll
    for (int off = 32; off > 0; off >>= 1) s += __shfl_down(s, off, 64);
    __shared__ float w[4];
    if ((threadIdx.x & 63) == 0) w[threadIdx.x >> 6] = s;
    __syncthreads();
    if (threadIdx.x == 0) atomicAdd(accum, (w[0]+w[1]+w[2]+w[3]) * scale);
}

__global__ __launch_bounds__(128) void infs_kernel(
    const float* __restrict__ out1,   // dec_gen_s at ld 256
    const float* __restrict__ out3,   // corr_s at ld 256
    const float* __restrict__ pvar,   // ld 128
    const float* __restrict__ ratio_p,
    float* __restrict__ inf_s,        // ld 128
    float scale, float* __restrict__ accum)
{
    const int m = blockIdx.x, t = threadIdx.x;
    float ratio = ratio_p[0];
    float dgs = out1[(size_t)m*256 + t];
    float cs  = out3[(size_t)m*256 + t];
    float pv  = pvar[(size_t)m*128 + t];
    float delta = (cs - dgs) * ratio * pv;
    inf_s[(size_t)m*128 + t] = dgs + delta;
    float ss = delta * delta;
    #pragma unroll
    for (int off = 32; off > 0; off >>= 1) ss += __shfl_down(ss, off, 64);
    __shared__ float w2[2];
    if ((t & 63) == 0) w2[t >> 6] = ss;
    __syncthreads();
    if (t == 0) atomicAdd(accum, (w2[0] + w2[1]) * scale);
}

// transpose: dst[c*R + r] = src[r*C + c]; grid C blocks, R threads
__global__ void transpose_kernel(const float* __restrict__ src, float* __restrict__ dst, int R, int C)
{
    const int c = blockIdx.x, r = threadIdx.x;
    dst[(size_t)c*R + r] = src[(size_t)r*C + c];
}

__global__ void zero_kernel(float* acc) {
    if (threadIdx.x < 8) acc[threadIdx.x] = 0.f;
}

__global__ void total_kernel(const float* acc, float* out) {
    if (threadIdx.x == 0)
        out[0] = acc[0] + acc[1] + acc[2] + acc[3];
}

// ================= host =================
static inline void gemmF(const float* A, int lda, const float* W, int ldw, const float* bias,
                         float* C, int N, int K, int relu, hipStream_t s)
{
    dim3 g(16, (N + 63) / 64);
    gemm_kernel<<<g, 256, 0, s>>>(A, lda, W, ldw, bias, C, N, N, K, relu);
}

extern "C" void kernel_launch(void* const* d_in, const int* in_sizes, int n_in,
                              void* d_out, int out_size, void* d_ws, size_t ws_size,
                              hipStream_t stream)
{
    const float* sensory     = (const float*)d_in[0];
    const float* actions     = (const float*)d_in[1];
    const float* init_hidden = (const float*)d_in[2];
    const float* tW1 = (const float*)d_in[3];  const float* tb1 = (const float*)d_in[4];
    const float* tW2 = (const float*)d_in[5];  const float* tb2 = (const float*)d_in[6];
    const float* tW3 = (const float*)d_in[7];  const float* tb3 = (const float*)d_in[8];
    const float* enc_w = (const float*)d_in[9];  const float* enc_b = (const float*)d_in[10];
    const float* dec_w = (const float*)d_in[11]; const float* dec_b = (const float*)d_in[12];
    const float* q_w = (const float*)d_in[13];
    const float* k_w = (const float*)d_in[14];
    const float* v_w = (const float*)d_in[15];
    const float* mW1 = (const float*)d_in[16]; const float* mb1 = (const float*)d_in[17];
    const float* mW2 = (const float*)d_in[18]; const float* mb2 = (const float*)d_in[19];
    const float* mW3 = (const float*)d_in[20]; const float* mb3 = (const float*)d_in[21];
    const float* oW1 = (const float*)d_in[22]; const float* ob1 = (const float*)d_in[23];
    const float* oW2 = (const float*)d_in[24]; const float* ob2 = (const float*)d_in[25];
    const float* oW3 = (const float*)d_in[26]; const float* ob3 = (const float*)d_in[27];
    const float* sW1 = (const float*)d_in[28]; const float* sb1 = (const float*)d_in[29];
    const float* sW2 = (const float*)d_in[30]; const float* sb2 = (const float*)d_in[31];
    const float* sW3 = (const float*)d_in[32]; const float* sb3 = (const float*)d_in[33];
    const float* ratio = (const float*)d_in[34];
    float* out = (float*)d_out;

    // workspace layout (floats)
    float* Wsp = (float*)d_ws;
    size_t off = 0;
    float* acc  = Wsp + off; off += 16;
    float* a1   = Wsp + off; off += (size_t)1024*128;
    float* a2   = Wsp + off; off += (size_t)1024*128;
    float* trans= Wsp + off; off += (size_t)1024*16384;
    float* structural = Wsp + off; off += (size_t)1024*128;
    float* encoded    = Wsp + off; off += (size_t)1024*128;
    float* out1 = Wsp + off; off += (size_t)1024*256;
    float* out2 = Wsp + off; off += (size_t)1024*256;
    float* out3 = Wsp + off; off += (size_t)1024*256;
    float* out4 = Wsp + off; off += (size_t)1024*256;
    float* pvar = Wsp + off; off += (size_t)1024*128;
    float* infs = Wsp + off; off += (size_t)1024*128;
    float* deco = Wsp + off; off += (size_t)1024*512;
    float* T2   = Wsp + off; off += (size_t)256*256;
    float* T3   = Wsp + off; off += (size_t)128*256;

    zero_kernel<<<1, 64, 0, stream>>>(acc);
    transpose_kernel<<<256, 256, 0, stream>>>(mW2, T2, 256, 256);  // T2[j*256+i]=mW2[i*256+j]
    transpose_kernel<<<128, 256, 0, stream>>>(mW3, T3, 256, 128);  // T3[k*256+j]=mW3[j*128+k]

    // PathIntegration transitions MLP
    gemmF(actions, 32, tW1, 128, tb1, a1, 128, 32, 1, stream);
    gemmF(a1, 128, tW2, 128, tb2, a2, 128, 128, 1, stream);
    gemmF(a2, 128, tW3, 16384, tb3, trans, 16384, 128, 0, stream);
    // encoder (linear, no relu)
    gemmF(sensory, 512, enc_w, 128, enc_b, encoded, 128, 512, 0, stream);
    // scan
    scan_kernel2<<<8, 512, 0, stream>>>(trans, init_hidden, structural);

    // generative: retrieve(structural, 0)
    fused_retrieve_kernel<<<128, 256, 0, stream>>>(structural, 128, nullptr, 0, q_w,
        mW1, mb1, mW2, mb2, mW3, mb3, oW1, ob1, oW2, ob2, oW3, ob3, out1);
    gemmF(out1 + 128, 256, dec_w, 512, dec_b, deco, 512, 128, 0, stream);
    mse_kernel<<<1024, 256, 0, stream>>>(deco, 512, sensory, 512, 512, 1.f/524288.f, acc + 0);

    // relational: retrieve(0, encoded) x2 -> scale 2
    fused_retrieve_kernel<<<128, 256, 0, stream>>>(nullptr, 0, encoded, 128, q_w,
        mW1, mb1, mW2, mb2, mW3, mb3, oW1, ob1, oW2, ob2, oW3, ob3, out2);
    mse_kernel<<<1024, 256, 0, stream>>>(out2, 256, structural, 128, 128, 2.f/131072.f, acc + 1);

    // consistency: retrieve(dec_gen_s, encoded)
    fused_retrieve_kernel<<<128, 256, 0, stream>>>(out1, 256, encoded, 128, q_w,
        mW1, mb1, mW2, mb2, mW3, mb3, oW1, ob1, oW2, ob2, oW3, ob3, out3);
    fused_svar_kernel<<<128, 256, 0, stream>>>(out3, out1, encoded,
        sW1, sb1, sW2, sb2, sW3, sb3, pvar);
    infs_kernel<<<1024, 128, 0, stream>>>(out1, out3, pvar, ratio, infs, 1.f/131072.f, acc + 2);

    // inference: retrieve(inf_s, 0)
    fused_retrieve_kernel<<<128, 256, 0, stream>>>(infs, 128, nullptr, 0, q_w,
        mW1, mb1, mW2, mb2, mW3, mb3, oW1, ob1, oW2, ob2, oW3, ob3, out4);
    gemmF(out4 + 128, 256, dec_w, 512, dec_b, deco, 512, 128, 0, stream);
    mse_kernel<<<1024, 256, 0, stream>>>(deco, 512, sensory, 512, 512, 1.f/524288.f, acc + 3);

    // fast-weight memory grads (keys/vals fused in)
    fused_grad_kernel<<<256, 256, 0, stream>>>(out4, encoded, k_w, v_w,
        mW1, mb1, mW2, mb2, mW3, mb3, T2, T3, out);

    total_kernel<<<1, 64, 0, stream>>>(acc, out);
}